// Round 8
// baseline (2297.952 us; speedup 1.0000x reference)
//
#include <hip/hip_runtime.h>
#include <hip/hip_bf16.h>

#define BATCH 1024
#define HID   512
#define OUTW  348   // 12 * (8+6+4+11)

using short8 = __attribute__((ext_vector_type(8))) short;
using bf16x8 = __attribute__((ext_vector_type(8))) __bf16;
using f32x4  = __attribute__((ext_vector_type(4))) float;

__device__ __forceinline__ float bf2f(unsigned short u) {
  union { unsigned int i; float f; } x; x.i = ((unsigned int)u) << 16; return x.f;
}
__device__ __forceinline__ unsigned short f2bf(float f) {
  __hip_bfloat16 b = __float2bfloat16(f);
  return __builtin_bit_cast(unsigned short, b);
}
__device__ __forceinline__ float sigm(float x) { return 1.0f / (1.0f + __expf(-x)); }

__device__ __forceinline__ f32x4 mfma_bf16(short8 a, short8 b, f32x4 c) {
  return __builtin_amdgcn_mfma_f32_16x16x32_bf16(
      __builtin_bit_cast(bf16x8, a), __builtin_bit_cast(bf16x8, b), c, 0, 0, 0);
}

typedef const __attribute__((address_space(1))) unsigned int* gas_p;
typedef __attribute__((address_space(3))) unsigned int* las_p;
__device__ __forceinline__ void gload16(const void* g, void* l) {
  __builtin_amdgcn_global_load_lds((gas_p)g, (las_p)l, 16, 0, 0);
}

// ---------------- setup kernels ----------------

__global__ void k_convert(const float* __restrict__ src, unsigned short* __restrict__ dst, int n) {
  int i = (blockIdx.x * blockDim.x + threadIdx.x) * 4;
  if (i + 3 < n) {
    float4 v = *(const float4*)(src + i);
    dst[i + 0] = f2bf(v.x); dst[i + 1] = f2bf(v.y);
    dst[i + 2] = f2bf(v.z); dst[i + 3] = f2bf(v.w);
  } else {
    for (int j = 0; j < 4 && i + j < n; ++j) dst[i + j] = f2bf(src[i + j]);
  }
}

// Wqp[128][512] bf16: rows 0..63 = Wcurr, 64..127 = Wprev
__global__ void k_wqp(const float* __restrict__ Wcurr, const float* __restrict__ Wprev,
                      unsigned short* __restrict__ dst) {
  int i = blockIdx.x * blockDim.x + threadIdx.x;  // < 128*512
  int row = i >> 9, col = i & 511;
  float v = (row < 64) ? Wcurr[row * 512 + col] : Wprev[(row - 64) * 512 + col];
  dst[i] = f2bf(v);
}

__global__ void k_bias(const float* __restrict__ bih, const float* __restrict__ bhh,
                       float* __restrict__ bsum) {
  int i = blockIdx.x * blockDim.x + threadIdx.x;
  if (i < 4096) bsum[i] = bih[i] + bhh[i];
}

__global__ void k_zero(uint4* __restrict__ p, int n16) {
  int i = blockIdx.x * blockDim.x + threadIdx.x;
  if (i < n16) p[i] = make_uint4(0u, 0u, 0u, 0u);
}

// P[0][r][a] = bprev[a]
__global__ void k_p0(float* __restrict__ P, const float* __restrict__ bprev) {
  int i = blockIdx.x * blockDim.x + threadIdx.x;  // < 1024*64
  P[i] = bprev[i & 63];
}

// ---------------- gates dispatch ----------------
// Tile: BM=32 batch rows x 16 cells (64 gate-cols: col = cell4*4 + gate), BK=64, K=1024.
// Grid 1024 GEMM blocks (4/CU) + optional 32 classifier blocks. Block 256 thr, 4 waves:
// wave (wm,wn) = rows wm*16..+16, cells wn*8..+8 (2 n-tiles of 16 gate-cols).
// Counted-vmcnt 2-barrier K-loop: stage(kt+1) loads stay in flight across barrier (T3/T4).

struct GJob {
  const unsigned short *X, *H, *Wih, *Whh;
  const float *bias;
  float *C;
  unsigned short *Hout;
};
struct CJob {
  const unsigned short* h;
  const float *Wc, *bc;
  float* out;
  int obase;
};

__device__ __forceinline__ void run_gemm(const GJob& j, int lb,
                                         unsigned short (*Ab)[2048],
                                         unsigned short (*Bb)[4096]) {
  const int tid = threadIdx.x, w = tid >> 6, lane = tid & 63;
  const int wm = w & 1, wn = w >> 1;
  // XCD-affine: nt = (lb&7)*4 + ((lb>>3)&3) in [0,32); mt = lb>>5 in [0,32)
  const int mt = lb >> 5;
  const int nt = (lb & 7) * 4 + ((lb >> 3) & 3);
  const int m0 = mt * 32;
  const int n0 = nt * 16;
  const int l16 = lane & 15, kg = lane >> 4;

  auto stage = [&](int kt, int buf) {
    const unsigned short* Asrc = (kt < 8) ? j.X : j.H;
    const unsigned short* Wsrc = (kt < 8) ? j.Wih : j.Whh;
    const int k0 = (kt & 7) * 64;
    {  // A: 32 rows x 64 elems = 4KB, 1 load/thread
      int s = tid, row = s >> 3;
      int ke = ((s & 7) ^ (row & 7)) << 3;  // pre-swizzled source offset
      gload16(Asrc + (size_t)(m0 + row) * HID + k0 + ke, &Ab[buf][s * 8]);
    }
#pragma unroll
    for (int i = 0; i < 2; ++i) {  // B: 64 gate-rows (cell*4+g) x 64 = 8KB
      int s = i * 256 + tid;
      int gr = s >> 3;             // 0..63 = cell*4 + gate
      int cell = gr >> 2, g = gr & 3;
      int ke = ((s & 7) ^ (gr & 7)) << 3;
      gload16(Wsrc + (size_t)(g * HID + n0 + cell) * HID + k0 + ke, &Bb[buf][s * 8]);
    }
  };

  f32x4 acc[2];
  acc[0] = (f32x4)(0.0f); acc[1] = (f32x4)(0.0f);

  stage(0, 0);
  for (int kt = 0; kt < 16; ++kt) {
    asm volatile("s_waitcnt lgkmcnt(0)" ::: "memory");  // all ds_reads of prev iter retired
    __builtin_amdgcn_s_barrier();                       // safe to overwrite buf (kt+1)&1
    if (kt < 15) {
      stage(kt + 1, (kt + 1) & 1);
      asm volatile("s_waitcnt vmcnt(3)" ::: "memory");  // kt's 3 loads done; kt+1's stay in flight
    } else {
      asm volatile("s_waitcnt vmcnt(0)" ::: "memory");
    }
    __builtin_amdgcn_s_barrier();                       // buf(kt) visible to all
    __builtin_amdgcn_sched_barrier(0);                  // don't hoist ds_reads above
    const int buf = kt & 1;
    const int ar = wm * 16 + l16;
    const char* abase = (const char*)&Ab[buf][0] + ar * 128;
    const char* bbase = (const char*)&Bb[buf][0];
#pragma unroll
    for (int ko = 0; ko < 2; ++ko) {
      const int kb = ko * 64 + kg * 16;
      short8 a = *(const short8*)(abase + (kb ^ ((ar & 7) << 4)));
#pragma unroll
      for (int t = 0; t < 2; ++t) {
        const int br = wn * 32 + t * 16 + l16;
        short8 b = *(const short8*)(bbase + br * 128 + (kb ^ ((br & 7) << 4)));
        acc[t] = mfma_bf16(a, b, acc[t]);
      }
    }
  }

  // epilogue: col l16 = c4*4 + g; gather 4 gates via 4-lane shfl; g==0 updates cell
  const int g = l16 & 3;
#pragma unroll
  for (int t = 0; t < 2; ++t) {
    const int cell = n0 + wn * 8 + t * 4 + (l16 >> 2);
    const float bs = j.bias[g * HID + cell];
#pragma unroll
    for (int r = 0; r < 4; ++r) {
      float val = acc[t][r] + bs;
      float gf = __shfl(val, (lane & ~3) + 1);
      float gg = __shfl(val, (lane & ~3) + 2);
      float go = __shfl(val, (lane & ~3) + 3);
      if (g == 0) {
        const int m = m0 + wm * 16 + kg * 4 + r;
        float cold = j.C[m * HID + cell];
        float cn = sigm(gf) * cold + sigm(val) * tanhf(gg);
        float hn = sigm(go) * tanhf(cn);
        j.C[m * HID + cell] = cn;
        j.Hout[m * HID + cell] = f2bf(hn);
      }
    }
  }
}

template <int S>
__device__ __forceinline__ void run_cls(const CJob& c, int cb) {
  const int w = threadIdx.x >> 6, lane = threadIdx.x & 63;
#pragma unroll
  for (int i = 0; i < 8; ++i) {
    const int r = (cb * 4 + w) * 8 + i;
    short8 hv = *(const short8*)(c.h + r * HID + lane * 8);
    float hf[8];
#pragma unroll
    for (int j = 0; j < 8; ++j) hf[j] = bf2f((unsigned short)hv[j]);
    float logit[S];
#pragma unroll
    for (int s = 0; s < S; ++s) {
      const float* wr = c.Wc + s * HID + lane * 8;
      float p = 0.f;
#pragma unroll
      for (int j = 0; j < 8; ++j) p += hf[j] * wr[j];
#pragma unroll
      for (int off = 32; off; off >>= 1) p += __shfl_xor(p, off);
      logit[s] = p + c.bc[s];
    }
    if (lane == 0) {
      float m = logit[0];
#pragma unroll
      for (int s = 1; s < S; ++s) m = fmaxf(m, logit[s]);
      float e[S], den = 0.f;
#pragma unroll
      for (int s = 0; s < S; ++s) { e[s] = __expf(logit[s] - m); den += e[s]; }
      float inv = 1.0f / den;
#pragma unroll
      for (int s = 0; s < S; ++s) c.out[r * OUTW + c.obase + s] = e[s] * inv;
    }
  }
}

template <int S>
__global__ __launch_bounds__(256, 4) void k_gates1(GJob A, CJob C) {
  __shared__ unsigned short Ab[2][2048];
  __shared__ unsigned short Bb[2][4096];
  const int b = blockIdx.x;
  if (b < 1024) {
    run_gemm(A, b, Ab, Bb);
  } else {
    if constexpr (S > 0) run_cls<S>(C, b - 1024);
  }
}

// ---------------- anchor: [Q||Pnew] = h1 @ Wqp^T, then scores + out + X embed ----------------
// Grid 64 blocks x 16 rows, 256 thr (4 waves). Wave w: cols w*32..+32 (2 n-tiles).
__global__ __launch_bounds__(256) void k_anchor2(
    const unsigned short* __restrict__ h1,
    const unsigned short* __restrict__ Wqp,
    const float* __restrict__ bcurr, const float* __restrict__ bprev,
    const float* __restrict__ vv, const float* __restrict__ Wanc,
    const float* __restrict__ banc,
    float* __restrict__ P, float* __restrict__ out,
    unsigned short* __restrict__ X, int cyc) {
  __shared__ unsigned short Ab[2][1024];   // 16 rows x 64
  __shared__ unsigned short Bb[2][8192];   // 128 rows x 64
  __shared__ float Qs[16][64];
  __shared__ float ss[16][12];
  const int tid = threadIdx.x, w = tid >> 6, lane = tid & 63;
  const int l16 = lane & 15, kg = lane >> 4;
  const int m0 = blockIdx.x * 16;

  auto stage = [&](int kt, int buf) {
    const int k0 = kt * 64;
    if (tid < 128) {
      int s = tid, row = s >> 3;
      int ke = ((s & 7) ^ (row & 7)) << 3;
      gload16(h1 + (size_t)(m0 + row) * HID + k0 + ke, &Ab[buf][s * 8]);
    }
#pragma unroll
    for (int i = 0; i < 4; ++i) {
      int s = i * 256 + tid, row = s >> 3;   // 0..127
      int ke = ((s & 7) ^ (row & 7)) << 3;
      gload16(Wqp + (size_t)row * HID + k0 + ke, &Bb[buf][s * 8]);
    }
  };

  f32x4 acc[2];
  acc[0] = (f32x4)(0.0f); acc[1] = (f32x4)(0.0f);
  stage(0, 0);
  for (int kt = 0; kt < 8; ++kt) {
    __syncthreads();
    if (kt < 7) stage(kt + 1, (kt + 1) & 1);
    const int buf = kt & 1;
#pragma unroll
    for (int ko = 0; ko < 2; ++ko) {
      const int kb = ko * 64 + kg * 16;
      const int ar = l16;
      short8 a = *(const short8*)((const char*)&Ab[buf][0] + ar * 128 + (kb ^ ((ar & 7) << 4)));
#pragma unroll
      for (int t = 0; t < 2; ++t) {
        const int br = w * 32 + t * 16 + l16;
        short8 b = *(const short8*)((const char*)&Bb[buf][0] + br * 128 + (kb ^ ((br & 7) << 4)));
        acc[t] = mfma_bf16(a, b, acc[t]);
      }
    }
  }

#pragma unroll
  for (int t = 0; t < 2; ++t) {
    const int col = w * 32 + t * 16 + l16;     // 0..127
#pragma unroll
    for (int r = 0; r < 4; ++r) {
      const int lr = kg * 4 + r;               // local row 0..15
      float val = acc[t][r] + (col < 64 ? bcurr[col] : bprev[col - 64]);
      if (col < 64) Qs[lr][col] = val;
      else if (cyc + 1 < 12) P[(size_t)(cyc + 1) * (BATCH * 64) + (m0 + lr) * 64 + (col - 64)] = val;
    }
  }
  __syncthreads();

  // scores: wave w handles rows w*4..+3
  for (int rr = 0; rr < 4; ++rr) {
    const int lr = w * 4 + rr;
    const float q = Qs[lr][lane];
    float skv = 0.f;
    for (int k = 0; k < cyc; ++k) {
      float tt = tanhf(P[(size_t)k * (BATCH * 64) + (m0 + lr) * 64 + lane] + q) * vv[lane];
#pragma unroll
      for (int off = 32; off; off >>= 1) tt += __shfl_xor(tt, off);
      float sk = sigm(tt);
      if (lane == k) skv = sk;
      if (lane == 0) ss[lr][k] = sk;
    }
    if (lane < 11) out[(size_t)(m0 + lr) * OUTW + cyc * 29 + 18 + lane] = (lane < cyc) ? skv : 0.f;
  }
  __syncthreads();

  // X embed: thread -> row tid>>4, d-range (tid&15)*32..+32
  {
    const int row = tid >> 4, dseg = tid & 15;
    for (int jj = 0; jj < 32; ++jj) {
      const int d = dseg * 32 + jj;
      float x = banc[d];
      for (int k = 0; k < cyc; ++k) x += ss[row][k] * Wanc[d * 11 + k];
      X[(size_t)(m0 + row) * HID + d] = f2bf(x);
    }
  }
}

// ---------------- launcher ----------------

extern "C" void kernel_launch(void* const* d_in, const int* in_sizes, int n_in,
                              void* d_out, int out_size, void* d_ws, size_t ws_size,
                              hipStream_t stream) {
  const float* x0    = (const float*)d_in[0];
  const float* lWih  = (const float*)d_in[1];
  const float* lWhh  = (const float*)d_in[2];
  const float* lbih  = (const float*)d_in[3];
  const float* lbhh  = (const float*)d_in[4];
  const float* Wc0   = (const float*)d_in[5];
  const float* bc0   = (const float*)d_in[6];
  const float* Wc1   = (const float*)d_in[7];
  const float* bc1   = (const float*)d_in[8];
  const float* Wc2   = (const float*)d_in[9];
  const float* bc2   = (const float*)d_in[10];
  const float* Wprev = (const float*)d_in[11];
  const float* bprev = (const float*)d_in[12];
  const float* Wcurr = (const float*)d_in[13];
  const float* bcurr = (const float*)d_in[14];
  const float* Wanc  = (const float*)d_in[15];
  const float* banc  = (const float*)d_in[16];
  const float* v     = (const float*)d_in[17];
  float* out = (float*)d_out;

  const size_t NW  = 2 * 2048 * 512;
  const size_t NBH = (size_t)BATCH * HID;

  char* ws = (char*)d_ws;
  size_t off = 0;
  auto alloc = [&](size_t bytes) { char* p = ws + off; off += (bytes + 255) & ~(size_t)255; return p; };
  unsigned short* Wih_b = (unsigned short*)alloc(NW * 2);
  unsigned short* Whh_b = (unsigned short*)alloc(NW * 2);
  unsigned short* Wqp_b = (unsigned short*)alloc(128 * 512 * 2);
  float*          biasS = (float*)alloc(4096 * 4);
  unsigned short* Xb    = (unsigned short*)alloc(NBH * 2);
  unsigned short* Hb0   = (unsigned short*)alloc(2 * NBH * 2);
  unsigned short* Hb1   = (unsigned short*)alloc(2 * NBH * 2);
  float*          C0    = (float*)alloc(NBH * 4);
  float*          C1    = (float*)alloc(NBH * 4);
  float*          P     = (float*)alloc((size_t)12 * BATCH * 64 * 4);

  k_convert<<<dim3((NW / 4 + 255) / 256), dim3(256), 0, stream>>>(lWih, Wih_b, (int)NW);
  k_convert<<<dim3((NW / 4 + 255) / 256), dim3(256), 0, stream>>>(lWhh, Whh_b, (int)NW);
  k_convert<<<dim3((NBH / 4 + 255) / 256), dim3(256), 0, stream>>>(x0, Xb, (int)NBH);
  k_wqp<<<dim3(256), dim3(256), 0, stream>>>(Wcurr, Wprev, Wqp_b);
  k_bias<<<dim3(16), dim3(256), 0, stream>>>(lbih, lbhh, biasS);
  {
    size_t zb = 2 * NBH * 2 + 2 * NBH * 2 + NBH * 4 + NBH * 4;  // Hb0,Hb1,C0,C1 contiguous
    int n16 = (int)(zb / 16);
    k_zero<<<dim3((n16 + 255) / 256), dim3(256), 0, stream>>>((uint4*)Hb0, n16);
  }
  k_p0<<<dim3(256), dim3(256), 0, stream>>>(P, bprev);

  // job builders (buffer parity: writer of step t uses parity (t+1)&1)
  auto jobL0 = [&](int u) {
    GJob j; j.X = Xb; j.H = Hb0 + (u & 1) * NBH;
    j.Wih = Wih_b; j.Whh = Whh_b; j.bias = biasS; j.C = C0;
    j.Hout = Hb0 + ((u + 1) & 1) * NBH; return j;
  };
  auto jobL1 = [&](int t) {
    GJob j; j.X = Hb0 + ((t + 1) & 1) * NBH; j.H = Hb1 + (t & 1) * NBH;
    j.Wih = Wih_b + 2048 * 512; j.Whh = Whh_b + 2048 * 512; j.bias = biasS + 2048; j.C = C1;
    j.Hout = Hb1 + ((t + 1) & 1) * NBH; return j;
  };
  auto h1of = [&](int t) { return (const unsigned short*)(Hb1 + ((t + 1) & 1) * NBH); };
  CJob nocls{};

  // prologue: L0(step 0)
  k_gates1<0><<<dim3(1024), dim3(256), 0, stream>>>(jobL0(0), nocls);

  for (int c = 0; c < 12; ++c) {
    const int t0 = 4 * c, t1 = t0 + 1, t2 = t0 + 2, t3 = t0 + 3;
    const int base = c * 29;
    CJob cls0{h1of(t0), Wc0, bc0, out, base};
    CJob cls1{h1of(t1), Wc1, bc1, out, base + 8};
    CJob cls2{h1of(t2), Wc2, bc2, out, base + 14};

    k_gates1<0><<<dim3(1024), dim3(256), 0, stream>>>(jobL1(t0), nocls);
    k_gates1<0><<<dim3(1024), dim3(256), 0, stream>>>(jobL0(t1), nocls);
    k_gates1<8><<<dim3(1056), dim3(256), 0, stream>>>(jobL1(t1), cls0);   // cls8 reads h1(t0)
    k_gates1<0><<<dim3(1024), dim3(256), 0, stream>>>(jobL0(t2), nocls);
    k_gates1<6><<<dim3(1056), dim3(256), 0, stream>>>(jobL1(t2), cls1);   // cls6 reads h1(t1)
    k_gates1<0><<<dim3(1024), dim3(256), 0, stream>>>(jobL0(t3), nocls);
    k_gates1<4><<<dim3(1056), dim3(256), 0, stream>>>(jobL1(t3), cls2);   // cls4 reads h1(t2)

    k_anchor2<<<dim3(64), dim3(256), 0, stream>>>(h1of(t3), Wqp_b, bcurr, bprev,
                                                  v, Wanc, banc, P, out, Xb, c);
    if (c < 11)
      k_gates1<0><<<dim3(1024), dim3(256), 0, stream>>>(jobL0(t3 + 1), nocls);
  }
  (void)in_sizes; (void)n_in; (void)out_size; (void)ws_size;
}

// Round 9
// 2176.688 us; speedup vs baseline: 1.0557x; 1.0557x over previous
//
#include <hip/hip_runtime.h>
#include <hip/hip_bf16.h>

#define BATCH 1024
#define HID   512
#define OUTW  348   // 12 * (8+6+4+11)

using short8 = __attribute__((ext_vector_type(8))) short;
using bf16x8 = __attribute__((ext_vector_type(8))) __bf16;
using f32x4  = __attribute__((ext_vector_type(4))) float;

__device__ __forceinline__ float bf2f(unsigned short u) {
  union { unsigned int i; float f; } x; x.i = ((unsigned int)u) << 16; return x.f;
}
__device__ __forceinline__ unsigned short f2bf(float f) {
  __hip_bfloat16 b = __float2bfloat16(f);
  return __builtin_bit_cast(unsigned short, b);
}
__device__ __forceinline__ float sigm(float x) { return 1.0f / (1.0f + __expf(-x)); }

__device__ __forceinline__ f32x4 mfma_bf16(short8 a, short8 b, f32x4 c) {
  return __builtin_amdgcn_mfma_f32_16x16x32_bf16(
      __builtin_bit_cast(bf16x8, a), __builtin_bit_cast(bf16x8, b), c, 0, 0, 0);
}

typedef const __attribute__((address_space(1))) unsigned int* gas_p;
typedef __attribute__((address_space(3))) unsigned int* las_p;
__device__ __forceinline__ void gload16(const void* g, void* l) {
  __builtin_amdgcn_global_load_lds((gas_p)g, (las_p)l, 16, 0, 0);
}

// ---------------- setup kernels ----------------

__global__ void k_convert(const float* __restrict__ src, unsigned short* __restrict__ dst, int n) {
  int i = (blockIdx.x * blockDim.x + threadIdx.x) * 4;
  if (i + 3 < n) {
    float4 v = *(const float4*)(src + i);
    dst[i + 0] = f2bf(v.x); dst[i + 1] = f2bf(v.y);
    dst[i + 2] = f2bf(v.z); dst[i + 3] = f2bf(v.w);
  } else {
    for (int j = 0; j < 4 && i + j < n; ++j) dst[i + j] = f2bf(src[i + j]);
  }
}

// Wqp[128][512] bf16: rows 0..63 = Wcurr, 64..127 = Wprev
__global__ void k_wqp(const float* __restrict__ Wcurr, const float* __restrict__ Wprev,
                      unsigned short* __restrict__ dst) {
  int i = blockIdx.x * blockDim.x + threadIdx.x;  // < 128*512
  int row = i >> 9, col = i & 511;
  float v = (row < 64) ? Wcurr[row * 512 + col] : Wprev[(row - 64) * 512 + col];
  dst[i] = f2bf(v);
}

__global__ void k_bias(const float* __restrict__ bih, const float* __restrict__ bhh,
                       float* __restrict__ bsum) {
  int i = blockIdx.x * blockDim.x + threadIdx.x;
  if (i < 4096) bsum[i] = bih[i] + bhh[i];
}

__global__ void k_zero(uint4* __restrict__ p, int n16) {
  int i = blockIdx.x * blockDim.x + threadIdx.x;
  if (i < n16) p[i] = make_uint4(0u, 0u, 0u, 0u);
}

// P[0][r][a] = bprev[a]
__global__ void k_p0(float* __restrict__ P, const float* __restrict__ bprev) {
  int i = blockIdx.x * blockDim.x + threadIdx.x;  // < 1024*64
  P[i] = bprev[i & 63];
}

// ---------------- gates dispatch ----------------
// Tile: BM=32 batch rows x 16 cells (64 gate-cols: col = cell4*4 + gate), BK=64, K=1024.
// Grid 1024 GEMM blocks (exactly 4/CU) + optional 32 classifier blocks. 256 thr, 4 waves:
// wave (wm,wn) = rows wm*16..+16, cells wn*8..+8.
// Depth-2-ahead software pipeline: 3-buffer LDS ring, counted vmcnt (6 steady / 3 / 0 tail)
// keeps two stages' global_load_lds in flight across every barrier.

struct GJob {
  const unsigned short *X, *H, *Wih, *Whh;
  const float *bias;
  float *C;
  unsigned short *Hout;
};
struct CJob {
  const unsigned short* h;
  const float *Wc, *bc;
  float* out;
  int obase;
};

__device__ __forceinline__ void run_gemm(const GJob& j, int lb,
                                         unsigned short (*Ab)[2048],
                                         unsigned short (*Bb)[4096]) {
  const int tid = threadIdx.x, w = tid >> 6, lane = tid & 63;
  const int wm = w & 1, wn = w >> 1;
  // XCD-affine: nt = (lb&7)*4 + ((lb>>3)&3) in [0,32); mt = lb>>5 in [0,32)
  const int mt = lb >> 5;
  const int nt = (lb & 7) * 4 + ((lb >> 3) & 3);
  const int m0 = mt * 32;
  const int n0 = nt * 16;
  const int l16 = lane & 15, kg = lane >> 4;

  auto stage = [&](int kt, int buf) {
    const unsigned short* Asrc = (kt < 8) ? j.X : j.H;
    const unsigned short* Wsrc = (kt < 8) ? j.Wih : j.Whh;
    const int k0 = (kt & 7) * 64;
    {  // A: 32 rows x 64 elems = 4KB, 1 load/thread
      int s = tid, row = s >> 3;
      int ke = ((s & 7) ^ (row & 7)) << 3;  // pre-swizzled source offset
      gload16(Asrc + (size_t)(m0 + row) * HID + k0 + ke, &Ab[buf][s * 8]);
    }
#pragma unroll
    for (int i = 0; i < 2; ++i) {  // B: 64 gate-rows (cell*4+g) x 64 = 8KB
      int s = i * 256 + tid;
      int gr = s >> 3;             // 0..63 = cell*4 + gate
      int cell = gr >> 2, g = gr & 3;
      int ke = ((s & 7) ^ (gr & 7)) << 3;
      gload16(Wsrc + (size_t)(g * HID + n0 + cell) * HID + k0 + ke, &Bb[buf][s * 8]);
    }
  };

  f32x4 acc[2];
  acc[0] = (f32x4)(0.0f); acc[1] = (f32x4)(0.0f);

  stage(0, 0);
  stage(1, 1);
#pragma unroll
  for (int kt = 0; kt < 16; ++kt) {
    asm volatile("s_waitcnt lgkmcnt(0)" ::: "memory");  // own ds_reads of iter kt-1 retired
    __builtin_amdgcn_s_barrier();                       // all waves done with buf (kt+2)%3
    if (kt <= 13) {
      stage(kt + 2, (kt + 2) % 3);
      asm volatile("s_waitcnt vmcnt(6)" ::: "memory");  // kt's 3 loads done; kt+1,kt+2 in flight
    } else if (kt == 14) {
      asm volatile("s_waitcnt vmcnt(3)" ::: "memory");
    } else {
      asm volatile("s_waitcnt vmcnt(0)" ::: "memory");
    }
    __builtin_amdgcn_s_barrier();                       // buf(kt) visible to all waves
    __builtin_amdgcn_sched_barrier(0);                  // don't hoist ds_reads above
    const int buf = kt % 3;
    const int ar = wm * 16 + l16;
    const char* abase = (const char*)&Ab[buf][0] + ar * 128;
    const char* bbase = (const char*)&Bb[buf][0];
#pragma unroll
    for (int ko = 0; ko < 2; ++ko) {
      const int kb = ko * 64 + kg * 16;
      short8 a = *(const short8*)(abase + (kb ^ ((ar & 7) << 4)));
#pragma unroll
      for (int t = 0; t < 2; ++t) {
        const int br = wn * 32 + t * 16 + l16;
        short8 b = *(const short8*)(bbase + br * 128 + (kb ^ ((br & 7) << 4)));
        acc[t] = mfma_bf16(a, b, acc[t]);
      }
    }
  }

  // epilogue: col l16 = c4*4 + g; gather 4 gates via 4-lane shfl; g==0 updates cell
  const int g = l16 & 3;
#pragma unroll
  for (int t = 0; t < 2; ++t) {
    const int cell = n0 + wn * 8 + t * 4 + (l16 >> 2);
    const float bs = j.bias[g * HID + cell];
#pragma unroll
    for (int r = 0; r < 4; ++r) {
      float val = acc[t][r] + bs;
      float gf = __shfl(val, (lane & ~3) + 1);
      float gg = __shfl(val, (lane & ~3) + 2);
      float go = __shfl(val, (lane & ~3) + 3);
      if (g == 0) {
        const int m = m0 + wm * 16 + kg * 4 + r;
        float cold = j.C[m * HID + cell];
        float cn = sigm(gf) * cold + sigm(val) * tanhf(gg);
        float hn = sigm(go) * tanhf(cn);
        j.C[m * HID + cell] = cn;
        j.Hout[m * HID + cell] = f2bf(hn);
      }
    }
  }
}

template <int S>
__device__ __forceinline__ void run_cls(const CJob& c, int cb) {
  const int w = threadIdx.x >> 6, lane = threadIdx.x & 63;
#pragma unroll
  for (int i = 0; i < 8; ++i) {
    const int r = (cb * 4 + w) * 8 + i;
    short8 hv = *(const short8*)(c.h + r * HID + lane * 8);
    float hf[8];
#pragma unroll
    for (int j = 0; j < 8; ++j) hf[j] = bf2f((unsigned short)hv[j]);
    float logit[S];
#pragma unroll
    for (int s = 0; s < S; ++s) {
      const float* wr = c.Wc + s * HID + lane * 8;
      float p = 0.f;
#pragma unroll
      for (int j = 0; j < 8; ++j) p += hf[j] * wr[j];
#pragma unroll
      for (int off = 32; off; off >>= 1) p += __shfl_xor(p, off);
      logit[s] = p + c.bc[s];
    }
    if (lane == 0) {
      float m = logit[0];
#pragma unroll
      for (int s = 1; s < S; ++s) m = fmaxf(m, logit[s]);
      float e[S], den = 0.f;
#pragma unroll
      for (int s = 0; s < S; ++s) { e[s] = __expf(logit[s] - m); den += e[s]; }
      float inv = 1.0f / den;
#pragma unroll
      for (int s = 0; s < S; ++s) c.out[r * OUTW + c.obase + s] = e[s] * inv;
    }
  }
}

template <int S>
__global__ __launch_bounds__(256, 4) void k_gates1(GJob A, CJob C) {
  __shared__ unsigned short Ab[3][2048];
  __shared__ unsigned short Bb[3][4096];
  const int b = blockIdx.x;
  if (b < 1024) {
    run_gemm(A, b, Ab, Bb);
  } else {
    if constexpr (S > 0) run_cls<S>(C, b - 1024);
  }
}

// ---------------- anchor projections: [Q || Pnew] = h1 @ Wqp^T ----------------
__global__ __launch_bounds__(256) void k_qp(
    const unsigned short* __restrict__ h1,
    const unsigned short* __restrict__ Wqp,   // [128][512] bf16
    const float* __restrict__ bcurr, const float* __restrict__ bprev,
    float* __restrict__ Q,                    // [1024][64]
    float* __restrict__ P,                    // [12][1024][64]
    int cyc) {
  __shared__ unsigned short Ab[2][4096];
  __shared__ unsigned short Bb[2][1024];
  const int w = threadIdx.x >> 6, lane = threadIdx.x & 63;
  const int m0 = blockIdx.x * 64, n0 = blockIdx.y * 16;
  const int l16 = lane & 15, kg = lane >> 4;

  auto stage = [&](int kt, int buf) {
    const int k0 = kt * 64;
#pragma unroll
    for (int j = 0; j < 2; ++j) {
      int s = w * 128 + j * 64 + lane;
      int row = s >> 3;
      int ke = ((s & 7) ^ (row & 7)) << 3;
      gload16(h1 + (size_t)(m0 + row) * HID + k0 + ke, &Ab[buf][(w * 128 + j * 64) * 8]);
    }
    if (w < 2) {
      int s = w * 64 + lane;
      int row = s >> 3;
      int ke = ((s & 7) ^ (row & 7)) << 3;
      gload16(Wqp + (size_t)(n0 + row) * HID + k0 + ke, &Bb[buf][(w * 64) * 8]);
    }
  };

  f32x4 acc = (f32x4)(0.0f);
  stage(0, 0);
  for (int kt = 0; kt < 8; ++kt) {
    __syncthreads();
    if (kt < 7) stage(kt + 1, (kt + 1) & 1);
    const int buf = kt & 1;
#pragma unroll
    for (int ko = 0; ko < 2; ++ko) {
      const int acb = ko * 64 + kg * 16;
      const int ar = w * 16 + l16;
      short8 a = *(const short8*)&Ab[buf][ar * 64 + ((acb ^ ((ar & 7) << 4)) >> 1)];
      const int br = l16;
      short8 b = *(const short8*)&Bb[buf][br * 64 + ((acb ^ ((br & 7) << 4)) >> 1)];
      acc = mfma_bf16(a, b, acc);
    }
  }

  const int col = n0 + l16;
  const int r0 = m0 + w * 16 + kg * 4;
#pragma unroll
  for (int r = 0; r < 4; ++r) {
    const int m = r0 + r;
    float val = acc[r] + (col < 64 ? bcurr[col] : bprev[col - 64]);
    if (col < 64) Q[m * 64 + col] = val;
    else if (cyc + 1 < 12) P[(cyc + 1) * (BATCH * 64) + m * 64 + (col - 64)] = val;
  }
}

// ---------------- anchor scores + embedding ----------------
template <int CYC>
__global__ __launch_bounds__(256) void k_scores(
    const float* __restrict__ Q, const float* __restrict__ P,
    const float* __restrict__ vv, const float* __restrict__ Wanc,
    const float* __restrict__ banc, float* __restrict__ out,
    unsigned short* __restrict__ X) {
  const int w = threadIdx.x >> 6, lane = threadIdx.x & 63;
  const int r = blockIdx.x * 4 + w;
  const float q = Q[r * 64 + lane];
  const float vl = vv[lane];
  float sk[CYC > 0 ? CYC : 1];
#pragma unroll
  for (int k = 0; k < CYC; ++k) {
    float t = tanhf(P[k * (BATCH * 64) + r * 64 + lane] + q) * vl;
#pragma unroll
    for (int off = 32; off; off >>= 1) t += __shfl_xor(t, off);
    sk[k] = sigm(t);
  }
  float ov = 0.0f;
#pragma unroll
  for (int k = 0; k < 11; ++k)
    if (lane == k) ov = (k < CYC) ? sk[k] : 0.0f;
  if (lane < 11) out[r * OUTW + CYC * 29 + 18 + lane] = ov;

  const int d0 = lane * 8;
#pragma unroll
  for (int j = 0; j < 8; ++j) {
    const int d = d0 + j;
    float x = banc[d];
#pragma unroll
    for (int k = 0; k < CYC; ++k) x += sk[k] * Wanc[d * 11 + k];
    X[r * HID + d] = f2bf(x);
  }
}

// ---------------- launcher ----------------

extern "C" void kernel_launch(void* const* d_in, const int* in_sizes, int n_in,
                              void* d_out, int out_size, void* d_ws, size_t ws_size,
                              hipStream_t stream) {
  const float* x0    = (const float*)d_in[0];
  const float* lWih  = (const float*)d_in[1];
  const float* lWhh  = (const float*)d_in[2];
  const float* lbih  = (const float*)d_in[3];
  const float* lbhh  = (const float*)d_in[4];
  const float* Wc0   = (const float*)d_in[5];
  const float* bc0   = (const float*)d_in[6];
  const float* Wc1   = (const float*)d_in[7];
  const float* bc1   = (const float*)d_in[8];
  const float* Wc2   = (const float*)d_in[9];
  const float* bc2   = (const float*)d_in[10];
  const float* Wprev = (const float*)d_in[11];
  const float* bprev = (const float*)d_in[12];
  const float* Wcurr = (const float*)d_in[13];
  const float* bcurr = (const float*)d_in[14];
  const float* Wanc  = (const float*)d_in[15];
  const float* banc  = (const float*)d_in[16];
  const float* v     = (const float*)d_in[17];
  float* out = (float*)d_out;

  const size_t NW  = 2 * 2048 * 512;
  const size_t NBH = (size_t)BATCH * HID;

  char* ws = (char*)d_ws;
  size_t off = 0;
  auto alloc = [&](size_t bytes) { char* p = ws + off; off += (bytes + 255) & ~(size_t)255; return p; };
  unsigned short* Wih_b = (unsigned short*)alloc(NW * 2);
  unsigned short* Whh_b = (unsigned short*)alloc(NW * 2);
  unsigned short* Wqp_b = (unsigned short*)alloc(128 * 512 * 2);
  float*          biasS = (float*)alloc(4096 * 4);
  unsigned short* Xb    = (unsigned short*)alloc(NBH * 2);
  unsigned short* Hb0   = (unsigned short*)alloc(2 * NBH * 2);
  unsigned short* Hb1   = (unsigned short*)alloc(2 * NBH * 2);
  float*          C0    = (float*)alloc(NBH * 4);
  float*          C1    = (float*)alloc(NBH * 4);
  float*          P     = (float*)alloc((size_t)12 * BATCH * 64 * 4);
  float*          Qb    = (float*)alloc((size_t)BATCH * 64 * 4);

  k_convert<<<dim3((NW / 4 + 255) / 256), dim3(256), 0, stream>>>(lWih, Wih_b, (int)NW);
  k_convert<<<dim3((NW / 4 + 255) / 256), dim3(256), 0, stream>>>(lWhh, Whh_b, (int)NW);
  k_convert<<<dim3((NBH / 4 + 255) / 256), dim3(256), 0, stream>>>(x0, Xb, (int)NBH);
  k_wqp<<<dim3(256), dim3(256), 0, stream>>>(Wcurr, Wprev, Wqp_b);
  k_bias<<<dim3(16), dim3(256), 0, stream>>>(lbih, lbhh, biasS);
  {
    size_t zb = 2 * NBH * 2 + 2 * NBH * 2 + NBH * 4 + NBH * 4;  // Hb0,Hb1,C0,C1 contiguous
    int n16 = (int)(zb / 16);
    k_zero<<<dim3((n16 + 255) / 256), dim3(256), 0, stream>>>((uint4*)Hb0, n16);
  }
  k_p0<<<dim3(256), dim3(256), 0, stream>>>(P, bprev);

  // job builders (buffer parity: writer of step t uses parity (t+1)&1)
  auto jobL0 = [&](int u) {
    GJob j; j.X = Xb; j.H = Hb0 + (u & 1) * NBH;
    j.Wih = Wih_b; j.Whh = Whh_b; j.bias = biasS; j.C = C0;
    j.Hout = Hb0 + ((u + 1) & 1) * NBH; return j;
  };
  auto jobL1 = [&](int t) {
    GJob j; j.X = Hb0 + ((t + 1) & 1) * NBH; j.H = Hb1 + (t & 1) * NBH;
    j.Wih = Wih_b + 2048 * 512; j.Whh = Whh_b + 2048 * 512; j.bias = biasS + 2048; j.C = C1;
    j.Hout = Hb1 + ((t + 1) & 1) * NBH; return j;
  };
  auto h1of = [&](int t) { return (const unsigned short*)(Hb1 + ((t + 1) & 1) * NBH); };
  CJob nocls{};

  // prologue: L0(step 0)
  k_gates1<0><<<dim3(1024), dim3(256), 0, stream>>>(jobL0(0), nocls);

  for (int c = 0; c < 12; ++c) {
    const int t0 = 4 * c, t1 = t0 + 1, t2 = t0 + 2, t3 = t0 + 3;
    const int base = c * 29;
    CJob cls0{h1of(t0), Wc0, bc0, out, base};
    CJob cls1{h1of(t1), Wc1, bc1, out, base + 8};
    CJob cls2{h1of(t2), Wc2, bc2, out, base + 14};

    k_gates1<0><<<dim3(1024), dim3(256), 0, stream>>>(jobL1(t0), nocls);
    k_gates1<0><<<dim3(1024), dim3(256), 0, stream>>>(jobL0(t1), nocls);
    k_gates1<8><<<dim3(1056), dim3(256), 0, stream>>>(jobL1(t1), cls0);   // cls8 reads h1(t0)
    k_gates1<0><<<dim3(1024), dim3(256), 0, stream>>>(jobL0(t2), nocls);
    k_gates1<6><<<dim3(1056), dim3(256), 0, stream>>>(jobL1(t2), cls1);   // cls6 reads h1(t1)
    k_gates1<0><<<dim3(1024), dim3(256), 0, stream>>>(jobL0(t3), nocls);
    k_gates1<4><<<dim3(1056), dim3(256), 0, stream>>>(jobL1(t3), cls2);   // cls4 reads h1(t2)

    k_qp<<<dim3(16, 8), dim3(256), 0, stream>>>(h1of(t3), Wqp_b, bcurr, bprev, Qb, P, c);
    switch (c) {
      case 0:  k_scores<0><<<dim3(256), dim3(256), 0, stream>>>(Qb, P, v, Wanc, banc, out, Xb); break;
      case 1:  k_scores<1><<<dim3(256), dim3(256), 0, stream>>>(Qb, P, v, Wanc, banc, out, Xb); break;
      case 2:  k_scores<2><<<dim3(256), dim3(256), 0, stream>>>(Qb, P, v, Wanc, banc, out, Xb); break;
      case 3:  k_scores<3><<<dim3(256), dim3(256), 0, stream>>>(Qb, P, v, Wanc, banc, out, Xb); break;
      case 4:  k_scores<4><<<dim3(256), dim3(256), 0, stream>>>(Qb, P, v, Wanc, banc, out, Xb); break;
      case 5:  k_scores<5><<<dim3(256), dim3(256), 0, stream>>>(Qb, P, v, Wanc, banc, out, Xb); break;
      case 6:  k_scores<6><<<dim3(256), dim3(256), 0, stream>>>(Qb, P, v, Wanc, banc, out, Xb); break;
      case 7:  k_scores<7><<<dim3(256), dim3(256), 0, stream>>>(Qb, P, v, Wanc, banc, out, Xb); break;
      case 8:  k_scores<8><<<dim3(256), dim3(256), 0, stream>>>(Qb, P, v, Wanc, banc, out, Xb); break;
      case 9:  k_scores<9><<<dim3(256), dim3(256), 0, stream>>>(Qb, P, v, Wanc, banc, out, Xb); break;
      case 10: k_scores<10><<<dim3(256), dim3(256), 0, stream>>>(Qb, P, v, Wanc, banc, out, Xb); break;
      default: k_scores<11><<<dim3(256), dim3(256), 0, stream>>>(Qb, P, v, Wanc, banc, out, Xb); break;
    }
    if (c < 11)
      k_gates1<0><<<dim3(1024), dim3(256), 0, stream>>>(jobL0(t3 + 1), nocls);
  }
  (void)in_sizes; (void)n_in; (void)out_size; (void)ws_size;
}